// Round 19
// baseline (1266.402 us; speedup 1.0000x reference)
//
#include <hip/hip_runtime.h>
#include <hip/hip_bf16.h>

#define HH 361
#define WW 720
#define HWP (HH*WW)          // 259920
#define CIN 11
#define CC 32
#define HD 16
#define EE 10
#define NBATCH ((HWP + 63) / 64)   // 4062
#define LN_EPS 1e-5f
#define SELU_ALPHA 1.6732632423543772f
#define SELU_SCALE 1.0507009873554805f
#define SELU_SA (SELU_SCALE * SELU_ALPHA)

// bf16 helpers (round-to-nearest-even pack; cheap unpacks from packed dwords)
static __device__ __forceinline__ unsigned int f2bf(float f) {
    unsigned int u = __float_as_uint(f);
    return (u + 0x7FFFu + ((u >> 16) & 1u)) >> 16;
}
static __device__ __forceinline__ float bflo(unsigned int u) {
    return __uint_as_float(u << 16);
}
static __device__ __forceinline__ float bfhi(unsigned int u) {
    return __uint_as_float(u & 0xffff0000u);
}
static __device__ __forceinline__ float selu_f(float v) {
    // fast SELU via v_exp_f32; abs err <= ~2e-6, invisible vs bf16 storage
    return v > 0.f ? SELU_SCALE * v : SELU_SA * (__expf(v) - 1.f);
}

// ---------------- zero accumulators ----------------
__global__ void zero_kernel(float* __restrict__ p) {
    int t = blockIdx.x * 256 + threadIdx.x;
    if (t < 40 + HD * EE * EE) p[t] = 0.f;
}

// ---------------- conv: INTERIOR blocks (x 1..10, y 1..21), guard-free ----------------
// r16-proven 4 rows x 16 ch / thread, half-split in grid.z. THIS ROUND: ci loop
// unroll 2 -> loads of ci+1 overlap FMA chain of ci (r18 diagnosis: 24% idle,
// loads serialized by unroll 1). Plain bounds; regs ~150 < 170 bucket.
__global__ __launch_bounds__(256) void conv_int_kernel(
    const float* __restrict__ inp, const float* __restrict__ emb_w,
    const float* __restrict__ emb_b, unsigned short* __restrict__ xout,
    float* __restrict__ stats)
{
    __shared__ float wlds[CIN * 25 * 16];   // 17.6 KB
    __shared__ float bsm[16];
    __shared__ float red[8];
    const int z = blockIdx.z;
    const int e = z >> 1, half = z & 1;
    const int tid = threadIdx.y * 64 + threadIdx.x;
    for (int t = tid; t < CIN * 25 * 16; t += 256) {
        int u = t & 15; int rest = t >> 4; int k25 = rest % 25; int ci = rest / 25;
        wlds[t] = emb_w[((half * 16 + u) * CIN + ci) * 25 + k25];
    }
    if (tid < 16) bsm[tid] = emb_b[half * 16 + tid];
    __syncthreads();

    const int w  = (blockIdx.x + 1) * 64 + threadIdx.x;    // 64..703
    const int h0 = (blockIdx.y + 1) * 16 + threadIdx.y * 4; // 16..348; halo in-range

    float acc[4][16];
    #pragma unroll
    for (int hs = 0; hs < 4; ++hs)
        #pragma unroll
        for (int c = 0; c < 16; ++c) acc[hs][c] = bsm[c];

    #pragma unroll 2
    for (int ci = 0; ci < CIN; ++ci) {
        const float* rp2 = inp + ((size_t)(e * CIN + ci)) * HWP + (size_t)(h0 - 2) * WW + (w - 2);
        float in[8][5];
        #pragma unroll
        for (int r = 0; r < 8; ++r) {
            float4 q = *(const float4*)rp2;
            in[r][0] = q.x; in[r][1] = q.y; in[r][2] = q.z; in[r][3] = q.w;
            in[r][4] = rp2[4];
            rp2 += WW;
        }
        #pragma unroll
        for (int kh = 0; kh < 5; ++kh) {
            #pragma unroll
            for (int kw = 0; kw < 5; ++kw) {
                const float* wp = &wlds[(ci * 25 + kh * 5 + kw) * 16];
                const float4 w0 = *(const float4*)(wp);
                const float4 w1 = *(const float4*)(wp + 4);
                const float4 w2 = *(const float4*)(wp + 8);
                const float4 w3 = *(const float4*)(wp + 12);
                #pragma unroll
                for (int hs = 0; hs < 4; ++hs) {
                    const float iv = in[hs + kh][kw];
                    acc[hs][0]  = fmaf(iv, w0.x, acc[hs][0]);
                    acc[hs][1]  = fmaf(iv, w0.y, acc[hs][1]);
                    acc[hs][2]  = fmaf(iv, w0.z, acc[hs][2]);
                    acc[hs][3]  = fmaf(iv, w0.w, acc[hs][3]);
                    acc[hs][4]  = fmaf(iv, w1.x, acc[hs][4]);
                    acc[hs][5]  = fmaf(iv, w1.y, acc[hs][5]);
                    acc[hs][6]  = fmaf(iv, w1.z, acc[hs][6]);
                    acc[hs][7]  = fmaf(iv, w1.w, acc[hs][7]);
                    acc[hs][8]  = fmaf(iv, w2.x, acc[hs][8]);
                    acc[hs][9]  = fmaf(iv, w2.y, acc[hs][9]);
                    acc[hs][10] = fmaf(iv, w2.z, acc[hs][10]);
                    acc[hs][11] = fmaf(iv, w2.w, acc[hs][11]);
                    acc[hs][12] = fmaf(iv, w3.x, acc[hs][12]);
                    acc[hs][13] = fmaf(iv, w3.y, acc[hs][13]);
                    acc[hs][14] = fmaf(iv, w3.z, acc[hs][14]);
                    acc[hs][15] = fmaf(iv, w3.w, acc[hs][15]);
                }
            }
        }
    }

    float s = 0.f, s2 = 0.f;
    #pragma unroll
    for (int hs = 0; hs < 4; ++hs) {
        const int h = h0 + hs;   // always < HH
        unsigned int pk[8];
        #pragma unroll
        for (int c = 0; c < 16; c += 2) {
            float v0 = selu_f(acc[hs][c]);
            float v1 = selu_f(acc[hs][c + 1]);
            s += v0 + v1; s2 = fmaf(v0, v0, s2); s2 = fmaf(v1, v1, s2);
            pk[c >> 1] = f2bf(v0) | (f2bf(v1) << 16);
        }
        uint4* dst = (uint4*)(xout + ((size_t)e * HWP + (size_t)h * WW + w) * CC + half * 16);
        dst[0] = make_uint4(pk[0], pk[1], pk[2], pk[3]);
        dst[1] = make_uint4(pk[4], pk[5], pk[6], pk[7]);
    }
    #pragma unroll
    for (int off = 32; off; off >>= 1) { s += __shfl_down(s, off); s2 += __shfl_down(s2, off); }
    if ((tid & 63) == 0) { red[tid >> 6] = s; red[4 + (tid >> 6)] = s2; }
    __syncthreads();
    if (tid == 0) {
        atomicAdd(&stats[e], red[0] + red[1] + red[2] + red[3]);
        atomicAdd(&stats[EE + e], red[4] + red[5] + red[6] + red[7]);
    }
}

// ---------------- conv: BOUNDARY blocks (frame), guarded path ----------------
__global__ __launch_bounds__(256) void conv_bnd_kernel(
    const float* __restrict__ inp, const float* __restrict__ emb_w,
    const float* __restrict__ emb_b, unsigned short* __restrict__ xout,
    float* __restrict__ stats)
{
    __shared__ float wlds[CIN * 25 * 16];
    __shared__ float bsm[16];
    __shared__ float red[8];
    const int z = blockIdx.y;
    const int e = z >> 1, half = z & 1;
    const int tid = threadIdx.y * 64 + threadIdx.x;
    for (int t = tid; t < CIN * 25 * 16; t += 256) {
        int u = t & 15; int rest = t >> 4; int k25 = rest % 25; int ci = rest / 25;
        wlds[t] = emb_w[((half * 16 + u) * CIN + ci) * 25 + k25];
    }
    if (tid < 16) bsm[tid] = emb_b[half * 16 + tid];
    __syncthreads();

    const int b = blockIdx.x;
    int bx, by;
    if (b < 23)      { bx = 0;      by = b; }
    else if (b < 46) { bx = 11;     by = b - 23; }
    else if (b < 56) { bx = b - 45; by = 0; }
    else             { bx = b - 55; by = 22; }

    const int w  = bx * 64 + threadIdx.x;
    const int h0 = by * 16 + threadIdx.y * 4;
    const bool active = (w < WW);

    int wl[5];
    if (active) {
        #pragma unroll
        for (int d = 0; d < 5; ++d) {
            int ww = w + d - 2; if (ww < 0) ww += WW; if (ww >= WW) ww -= WW; wl[d] = ww;
        }
    }

    float acc[4][16];
    #pragma unroll
    for (int hs = 0; hs < 4; ++hs)
        #pragma unroll
        for (int c = 0; c < 16; ++c) acc[hs][c] = bsm[c];

    if (active) {
        #pragma unroll 1
        for (int ci = 0; ci < CIN; ++ci) {
            const float* ip = inp + ((size_t)(e * CIN + ci)) * HWP;
            float in[8][5];
            #pragma unroll
            for (int r = 0; r < 8; ++r) {
                int hh = h0 + r - 2;
                bool v = (hh >= 0 && hh < HH);
                const float* rp = ip + (size_t)hh * WW;
                #pragma unroll
                for (int d = 0; d < 5; ++d) in[r][d] = v ? rp[wl[d]] : 0.f;
            }
            #pragma unroll
            for (int kh = 0; kh < 5; ++kh) {
                #pragma unroll
                for (int kw = 0; kw < 5; ++kw) {
                    const float* wp = &wlds[(ci * 25 + kh * 5 + kw) * 16];
                    const float4 w0 = *(const float4*)(wp);
                    const float4 w1 = *(const float4*)(wp + 4);
                    const float4 w2 = *(const float4*)(wp + 8);
                    const float4 w3 = *(const float4*)(wp + 12);
                    #pragma unroll
                    for (int hs = 0; hs < 4; ++hs) {
                        const float iv = in[hs + kh][kw];
                        acc[hs][0]  = fmaf(iv, w0.x, acc[hs][0]);
                        acc[hs][1]  = fmaf(iv, w0.y, acc[hs][1]);
                        acc[hs][2]  = fmaf(iv, w0.z, acc[hs][2]);
                        acc[hs][3]  = fmaf(iv, w0.w, acc[hs][3]);
                        acc[hs][4]  = fmaf(iv, w1.x, acc[hs][4]);
                        acc[hs][5]  = fmaf(iv, w1.y, acc[hs][5]);
                        acc[hs][6]  = fmaf(iv, w1.z, acc[hs][6]);
                        acc[hs][7]  = fmaf(iv, w1.w, acc[hs][7]);
                        acc[hs][8]  = fmaf(iv, w2.x, acc[hs][8]);
                        acc[hs][9]  = fmaf(iv, w2.y, acc[hs][9]);
                        acc[hs][10] = fmaf(iv, w2.z, acc[hs][10]);
                        acc[hs][11] = fmaf(iv, w2.w, acc[hs][11]);
                        acc[hs][12] = fmaf(iv, w3.x, acc[hs][12]);
                        acc[hs][13] = fmaf(iv, w3.y, acc[hs][13]);
                        acc[hs][14] = fmaf(iv, w3.z, acc[hs][14]);
                        acc[hs][15] = fmaf(iv, w3.w, acc[hs][15]);
                    }
                }
            }
        }
    }

    float s = 0.f, s2 = 0.f;
    #pragma unroll
    for (int hs = 0; hs < 4; ++hs) {
        const int h = h0 + hs;
        if (active && h < HH) {
            unsigned int pk[8];
            #pragma unroll
            for (int c = 0; c < 16; c += 2) {
                float v0 = selu_f(acc[hs][c]);
                float v1 = selu_f(acc[hs][c + 1]);
                s += v0 + v1; s2 = fmaf(v0, v0, s2); s2 = fmaf(v1, v1, s2);
                pk[c >> 1] = f2bf(v0) | (f2bf(v1) << 16);
            }
            uint4* dst = (uint4*)(xout + ((size_t)e * HWP + (size_t)h * WW + w) * CC + half * 16);
            dst[0] = make_uint4(pk[0], pk[1], pk[2], pk[3]);
            dst[1] = make_uint4(pk[4], pk[5], pk[6], pk[7]);
        }
    }
    #pragma unroll
    for (int off = 32; off; off >>= 1) { s += __shfl_down(s, off); s2 += __shfl_down(s2, off); }
    if ((tid & 63) == 0) { red[tid >> 6] = s; red[4 + (tid >> 6)] = s2; }
    __syncthreads();
    if (tid == 0) {
        atomicAdd(&stats[e], red[0] + red[1] + red[2] + red[3]);
        atomicAdd(&stats[EE + e], red[4] + red[5] + red[6] + red[7]);
    }
}

// ---------------- finalize LN stats ----------------
__global__ void ln_stats_kernel(float* __restrict__ stats) {
    int e = threadIdx.x;
    if (e < EE) {
        const float N = (float)CC * (float)HWP;
        float mu = stats[e] / N;
        float var = stats[EE + e] / N - mu * mu;
        stats[2 * EE + e] = mu;
        stats[3 * EE + e] = rsqrtf(var + LN_EPS);
    }
}

// ---------------- fused k,q + scores ----------------
__global__ __launch_bounds__(256) void scores_fused_kernel(
    const unsigned short* __restrict__ x, const float* __restrict__ ln_w,
    const float* __restrict__ ln_b, const float* __restrict__ wk,
    const float* __restrict__ wq, const float* __restrict__ stats,
    float* __restrict__ sacc)
{
    __shared__ float wksT[CC * HD], wqsT[CC * HD];   // [ch][c]
    __shared__ unsigned int stage[64][164];          // k at [e*8+d], q at [80+e*8+d]
    for (int t = threadIdx.x; t < CC * HD; t += 256) {
        int ch = t >> 4, c = t & 15;
        wksT[t] = wk[c * CC + ch];
        wqsT[t] = wq[c * CC + ch];
    }
    float mu[EE], rs[EE];
    #pragma unroll
    for (int e2 = 0; e2 < EE; ++e2) { mu[e2] = stats[2 * EE + e2]; rs[e2] = stats[3 * EE + e2]; }

    const int wv = threadIdx.x >> 6;
    const int lane = threadIdx.x & 63;
    const int pr = threadIdx.x >> 1;
    const int hf = threadIdx.x & 1;
    const int pi = pr / EE, pj = pr % EE;
    float acc[8] = {0.f,0.f,0.f,0.f,0.f,0.f,0.f,0.f};
    __syncthreads();

    #pragma unroll 1
    for (int b = blockIdx.x; b < NBATCH; b += gridDim.x) {
        const int pix = b * 64 + lane;
        const bool valid = pix < HWP;
        float lw[CC], lb[CC];
        #pragma unroll
        for (int ch = 0; ch < CC; ++ch) {
            lw[ch] = valid ? ln_w[(size_t)ch * HWP + pix] : 0.f;
            lb[ch] = valid ? ln_b[(size_t)ch * HWP + pix] : 0.f;
        }
        #pragma unroll 1
        for (int g = 0; g < 5; ++g) {
            unsigned int xr[2][16];
            #pragma unroll
            for (int eg = 0; eg < 2; ++eg) {
                const int e2 = g * 2 + eg;
                if (valid) {
                    const uint4* xp = (const uint4*)(x + ((size_t)e2 * HWP + pix) * CC);
                    uint4 a0 = xp[0], a1 = xp[1], a2 = xp[2], a3 = xp[3];
                    xr[eg][0]=a0.x; xr[eg][1]=a0.y; xr[eg][2]=a0.z; xr[eg][3]=a0.w;
                    xr[eg][4]=a1.x; xr[eg][5]=a1.y; xr[eg][6]=a1.z; xr[eg][7]=a1.w;
                    xr[eg][8]=a2.x; xr[eg][9]=a2.y; xr[eg][10]=a2.z; xr[eg][11]=a2.w;
                    xr[eg][12]=a3.x; xr[eg][13]=a3.y; xr[eg][14]=a3.z; xr[eg][15]=a3.w;
                } else {
                    #pragma unroll
                    for (int k2 = 0; k2 < 16; ++k2) xr[eg][k2] = 0u;
                }
            }
            float ka[2][4], qa[2][4];
            #pragma unroll
            for (int eg = 0; eg < 2; ++eg)
                #pragma unroll
                for (int u = 0; u < 4; ++u) { ka[eg][u] = 0.f; qa[eg][u] = 0.f; }
            #pragma unroll
            for (int ch = 0; ch < CC; ++ch) {
                const float4 wk4 = *(const float4*)&wksT[ch * HD + wv * 4];
                const float4 wq4 = *(const float4*)&wqsT[ch * HD + wv * 4];
                #pragma unroll
                for (int eg = 0; eg < 2; ++eg) {
                    const int e2 = g * 2 + eg;
                    unsigned int u = xr[eg][ch >> 1];
                    float xv = (ch & 1) ? bfhi(u) : bflo(u);
                    float lnv = fmaf((xv - mu[e2]) * rs[e2], lw[ch], lb[ch]);
                    ka[eg][0] = fmaf(wk4.x, lnv, ka[eg][0]);
                    ka[eg][1] = fmaf(wk4.y, lnv, ka[eg][1]);
                    ka[eg][2] = fmaf(wk4.z, lnv, ka[eg][2]);
                    ka[eg][3] = fmaf(wk4.w, lnv, ka[eg][3]);
                    qa[eg][0] = fmaf(wq4.x, lnv, qa[eg][0]);
                    qa[eg][1] = fmaf(wq4.y, lnv, qa[eg][1]);
                    qa[eg][2] = fmaf(wq4.z, lnv, qa[eg][2]);
                    qa[eg][3] = fmaf(wq4.w, lnv, qa[eg][3]);
                }
            }
            #pragma unroll
            for (int eg = 0; eg < 2; ++eg) {
                const int e2 = g * 2 + eg;
                uint2 kp, qp;
                kp.x = f2bf(fmaxf(ka[eg][0], 0.f)) | (f2bf(fmaxf(ka[eg][1], 0.f)) << 16);
                kp.y = f2bf(fmaxf(ka[eg][2], 0.f)) | (f2bf(fmaxf(ka[eg][3], 0.f)) << 16);
                qp.x = f2bf(fmaxf(qa[eg][0], 0.f)) | (f2bf(fmaxf(qa[eg][1], 0.f)) << 16);
                qp.y = f2bf(fmaxf(qa[eg][2], 0.f)) | (f2bf(fmaxf(qa[eg][3], 0.f)) << 16);
                *(uint2*)&stage[lane][e2 * 8 + wv * 2] = kp;
                *(uint2*)&stage[lane][80 + e2 * 8 + wv * 2] = qp;
            }
        }
        __syncthreads();
        if (pr < 100) {
            #pragma unroll 8
            for (int p = 0; p < 64; ++p) {
                uint4 kk = *(const uint4*)&stage[p][pi * 8 + hf * 4];
                uint4 qq = *(const uint4*)&stage[p][80 + pj * 8 + hf * 4];
                acc[0] = fmaf(bflo(kk.x), bflo(qq.x), acc[0]);
                acc[1] = fmaf(bfhi(kk.x), bfhi(qq.x), acc[1]);
                acc[2] = fmaf(bflo(kk.y), bflo(qq.y), acc[2]);
                acc[3] = fmaf(bfhi(kk.y), bfhi(qq.y), acc[3]);
                acc[4] = fmaf(bflo(kk.z), bflo(qq.z), acc[4]);
                acc[5] = fmaf(bfhi(kk.z), bfhi(qq.z), acc[5]);
                acc[6] = fmaf(bflo(kk.w), bflo(qq.w), acc[6]);
                acc[7] = fmaf(bfhi(kk.w), bfhi(qq.w), acc[7]);
            }
        }
        __syncthreads();
    }
    if (pr < 100) {
        #pragma unroll
        for (int c2 = 0; c2 < 8; ++c2)
            atomicAdd(&sacc[((hf * 8 + c2) * EE + pi) * EE + pj], acc[c2]);
    }
}

// ---------------- softmax over i + fold A = delta + w - 1/E ----------------
__global__ void softmax_kernel(const float* __restrict__ sacc, float* __restrict__ A)
{
    int t = threadIdx.x;
    if (t >= HD * EE) return;
    int c = t / EE, j = t - c * EE;
    const float norm = (float)(1.0 / 509.8234988357398);  // 1/sqrt(361*720)
    float sv[EE];
    float mx = -1e30f;
    #pragma unroll
    for (int i = 0; i < EE; ++i) { sv[i] = sacc[(c * EE + i) * EE + j] * norm; mx = fmaxf(mx, sv[i]); }
    float sum = 0.f;
    #pragma unroll
    for (int i = 0; i < EE; ++i) { sv[i] = expf(sv[i] - mx); sum += sv[i]; }
    float inv = 1.f / sum;
    #pragma unroll
    for (int i = 0; i < EE; ++i) {
        float wgt = sv[i] * inv;
        A[(c * EE + i) * EE + j] = wgt - (1.f / (float)EE) + (i == j ? 1.f : 0.f);
    }
}

// ---------------- fused final v3: 4-way head split, tv-accumulate, tiny state ----------------
__global__ __launch_bounds__(256) void final_kernel(
    const unsigned short* __restrict__ x, const float* __restrict__ ln_w,
    const float* __restrict__ ln_b, const float* __restrict__ wvw,
    const float* __restrict__ wo, const float* __restrict__ bo,
    const float* __restrict__ w_out, const float* __restrict__ b_out,
    const float* __restrict__ stats, const float* __restrict__ A,
    float* __restrict__ y)
{
    __shared__ float As_l[HD * 120];        // [c][e][j pad 12]  7.5 KB
    __shared__ float wvsT[CC * HD];         // [ch][c]           2 KB
    __shared__ float wos[HD * CC];          // [c][ch]           2 KB
    __shared__ float lwlds[64 * 36];        // [px][ch pad 36]   9 KB
    __shared__ float bos[CC];
    __shared__ float wouts[CC];
    const int tid = threadIdx.x;
    const int pixbase = blockIdx.x * 64;
    for (int t = tid; t < CC * HD; t += 256) {
        int ch = t >> 4, c = t & 15;
        wvsT[t] = wvw[c * CC + ch];
        wos[c * CC + ch] = wo[ch * HD + c];
    }
    for (int t = tid; t < HD * EE * EE; t += 256) {
        int c = t / 100, rest = t % 100;
        As_l[c * 120 + (rest / 10) * 12 + (rest % 10)] = A[t];
    }
    for (int t = tid; t < 64 * CC; t += 256) {
        int px = t & 63, ch = t >> 6;
        int pp = pixbase + px;
        lwlds[px * 36 + ch] = (pp < HWP) ? ln_w[(size_t)ch * HWP + pp] : 0.f;
    }
    if (tid < CC) { bos[tid] = bo[tid]; wouts[tid] = w_out[tid]; }
    __syncthreads();

    const int wvi = tid >> 6, lane = tid & 63;
    const int px = lane & 15;          // pixel slot within wave
    const int qg = lane >> 4;          // head/channel quarter 0..3
    const int pxl = wvi * 16 + px;     // local pixel 0..63
    const int pix = pixbase + pxl;
    const bool valid = pix < HWP;

    // ---- cb0/cb1 for this lane's 4 heads
    float cb0[4] = {0.f, 0.f, 0.f, 0.f}, cb1[4] = {0.f, 0.f, 0.f, 0.f};
    #pragma unroll
    for (int ch = 0; ch < CC; ++ch) {
        float lwv = lwlds[pxl * 36 + ch];
        float lbv = valid ? ln_b[(size_t)ch * HWP + pix] : 0.f;
        const float4 w4 = *(const float4*)&wvsT[ch * HD + qg * 4];
        cb1[0] = fmaf(w4.x, lwv, cb1[0]); cb1[1] = fmaf(w4.y, lwv, cb1[1]);
        cb1[2] = fmaf(w4.z, lwv, cb1[2]); cb1[3] = fmaf(w4.w, lwv, cb1[3]);
        cb0[0] = fmaf(w4.x, lbv, cb0[0]); cb0[1] = fmaf(w4.y, lbv, cb0[1]);
        cb0[2] = fmaf(w4.z, lbv, cb0[2]); cb0[3] = fmaf(w4.w, lbv, cb0[3]);
    }

    float tvacc[EE][4];
    #pragma unroll
    for (int j = 0; j < EE; ++j)
        #pragma unroll
        for (int r = 0; r < 4; ++r) tvacc[j][r] = 0.f;

    // ---- Phase A: members in pairs; v transient, folded into tvacc immediately
    #pragma unroll 1
    for (int ep = 0; ep < 5; ++ep) {
        const int e0 = 2 * ep, e1 = 2 * ep + 1;
        const float mu0 = stats[2 * EE + e0], rs0 = stats[3 * EE + e0];
        const float mu1 = stats[2 * EE + e1], rs1 = stats[3 * EE + e1];
        const uint4* xp0 = (const uint4*)(x + ((size_t)e0 * HWP + pix) * CC);
        const uint4* xp1 = (const uint4*)(x + ((size_t)e1 * HWP + pix) * CC);
        float a0[4] = {0.f, 0.f, 0.f, 0.f}, a1[4] = {0.f, 0.f, 0.f, 0.f};
        #pragma unroll
        for (int hx = 0; hx < 2; ++hx) {
            unsigned int xr0[8], xr1[8];
            if (valid) {
                uint4 b0 = xp0[2 * hx], b1 = xp0[2 * hx + 1];
                xr0[0]=b0.x; xr0[1]=b0.y; xr0[2]=b0.z; xr0[3]=b0.w;
                xr0[4]=b1.x; xr0[5]=b1.y; xr0[6]=b1.z; xr0[7]=b1.w;
                uint4 c0 = xp1[2 * hx], c1 = xp1[2 * hx + 1];
                xr1[0]=c0.x; xr1[1]=c0.y; xr1[2]=c0.z; xr1[3]=c0.w;
                xr1[4]=c1.x; xr1[5]=c1.y; xr1[6]=c1.z; xr1[7]=c1.w;
            } else {
                #pragma unroll
                for (int k2 = 0; k2 < 8; ++k2) { xr0[k2] = 0u; xr1[k2] = 0u; }
            }
            #pragma unroll
            for (int c2 = 0; c2 < 16; ++c2) {
                const int ch = hx * 16 + c2;
                const float lwv = lwlds[pxl * 36 + ch];
                const float4 w4 = *(const float4*)&wvsT[ch * HD + qg * 4];
                unsigned int u0 = xr0[c2 >> 1], u1 = xr1[c2 >> 1];
                float t0 = ((c2 & 1) ? bfhi(u0) : bflo(u0)) * lwv;
                float t1 = ((c2 & 1) ? bfhi(u1) : bflo(u1)) * lwv;
                a0[0] = fmaf(w4.x, t0, a0[0]); a0[1] = fmaf(w4.y, t0, a0[1]);
                a0[2] = fmaf(w4.z, t0, a0[2]); a0[3] = fmaf(w4.w, t0, a0[3]);
                a1[0] = fmaf(w4.x, t1, a1[0]); a1[1] = fmaf(w4.y, t1, a1[1]);
                a1[2] = fmaf(w4.z, t1, a1[2]); a1[3] = fmaf(w4.w, t1, a1[3]);
            }
        }
        const float mrs0 = mu0 * rs0, mrs1 = mu1 * rs1;
        #pragma unroll
        for (int r = 0; r < 4; ++r) {
            const float v0r = rs0 * a0[r] - mrs0 * cb1[r] + cb0[r];
            const float v1r = rs1 * a1[r] - mrs1 * cb1[r] + cb0[r];
            const float* p0 = &As_l[(qg * 4 + r) * 120 + e0 * 12];
            const float* p1 = &As_l[(qg * 4 + r) * 120 + e1 * 12];
            float4 A0a = *(const float4*)p0; float4 A0b = *(const float4*)(p0 + 4);
            float2 A0c = *(const float2*)(p0 + 8);
            float4 A1a = *(const float4*)p1; float4 A1b = *(const float4*)(p1 + 4);
            float2 A1c = *(const float2*)(p1 + 8);
            tvacc[0][r] = fmaf(A0a.x, v0r, fmaf(A1a.x, v1r, tvacc[0][r]));
            tvacc[1][r] = fmaf(A0a.y, v0r, fmaf(A1a.y, v1r, tvacc[1][r]));
            tvacc[2][r] = fmaf(A0a.z, v0r, fmaf(A1a.z, v1r, tvacc[2][r]));
            tvacc[3][r] = fmaf(A0a.w, v0r, fmaf(A1a.w, v1r, tvacc[3][r]));
            tvacc[4][r] = fmaf(A0b.x, v0r, fmaf(A1b.x, v1r, tvacc[4][r]));
            tvacc[5][r] = fmaf(A0b.y, v0r, fmaf(A1b.y, v1r, tvacc[5][r]));
            tvacc[6][r] = fmaf(A0b.z, v0r, fmaf(A1b.z, v1r, tvacc[6][r]));
            tvacc[7][r] = fmaf(A0b.w, v0r, fmaf(A1b.w, v1r, tvacc[7][r]));
            tvacc[8][r] = fmaf(A0c.x, v0r, fmaf(A1c.x, v1r, tvacc[8][r]));
            tvacc[9][r] = fmaf(A0c.y, v0r, fmaf(A1c.y, v1r, tvacc[9][r]));
        }
    }

    // ---- Phase B: per output member j (fully unrolled; tvacc static indices)
    const float boutv = b_out[0];
    #pragma unroll
    for (int j = 0; j < EE; ++j) {
        float tvj[16];
        #pragma unroll
        for (int c = 0; c < 16; ++c)
            tvj[c] = __shfl(tvacc[j][c & 3], (c >> 2) * 16 + px, 64);
        unsigned int xj[4];
        if (valid) {
            uint4 b = *(const uint4*)(x + ((size_t)j * HWP + pix) * CC + qg * 8);
            xj[0] = b.x; xj[1] = b.y; xj[2] = b.z; xj[3] = b.w;
        } else {
            #pragma unroll
            for (int k2 = 0; k2 < 4; ++k2) xj[k2] = 0u;
        }
        float o[8];
        #pragma unroll
        for (int k = 0; k < 8; ++k) {
            unsigned int u = xj[k >> 1];
            float xv = (k & 1) ? bfhi(u) : bflo(u);
            o[k] = bos[qg * 8 + k] + xv;
        }
        #pragma unroll
        for (int c = 0; c < 16; ++c) {
            const float tvc = tvj[c];
            const float4 wv0 = *(const float4*)&wos[c * CC + qg * 8];
            const float4 wv1 = *(const float4*)&wos[c * CC + qg * 8 + 4];
            o[0] = fmaf(wv0.x, tvc, o[0]); o[1] = fmaf(wv0.y, tvc, o[1]);
            o[2] = fmaf(wv0.z, tvc, o[2]); o[3] = fmaf(wv0.w, tvc, o[3]);
            o[4] = fmaf(wv1.x, tvc, o[4]); o[5] = fmaf(wv1.y, tvc, o[5]);
            o[6] = fmaf(wv1.z, tvc, o[6]); o[7] = fmaf(wv1.w, tvc, o[7]);
        }
        float yp = 0.f;
        #pragma unroll
        for (int k = 0; k < 8; ++k) yp = fmaf(wouts[qg * 8 + k], fmaxf(o[k], 0.f), yp);
        yp += __shfl_xor(yp, 16);
        yp += __shfl_xor(yp, 32);
        if (qg == 0 && valid) y[(size_t)j * HWP + pix] = yp + boutv;
    }
}

extern "C" void kernel_launch(void* const* d_in, const int* in_sizes, int n_in,
                              void* d_out, int out_size, void* d_ws, size_t ws_size,
                              hipStream_t stream)
{
    const float* inp   = (const float*)d_in[0];
    const float* emb_w = (const float*)d_in[1];
    const float* emb_b = (const float*)d_in[2];
    const float* ln_w  = (const float*)d_in[3];
    const float* ln_b  = (const float*)d_in[4];
    const float* wv    = (const float*)d_in[5];
    const float* wk    = (const float*)d_in[6];
    const float* wq    = (const float*)d_in[7];
    const float* wo    = (const float*)d_in[8];
    const float* bo    = (const float*)d_in[9];
    const float* w_out = (const float*)d_in[10];
    const float* b_out = (const float*)d_in[11];
    float* y = (float*)d_out;

    // ws: x bf16 channel-last [E][HW][32] = 166,348,800 B; then stats(40)+sacc(1600)+A(1600)
    unsigned short* xbuf = (unsigned short*)d_ws;
    float* stats = (float*)((char*)d_ws + (size_t)EE * HWP * CC * 2);
    float* sacc  = stats + 40;
    float* Amat  = sacc + HD * EE * EE;

    zero_kernel<<<7, 256, 0, stream>>>(stats);
    conv_int_kernel<<<dim3(10, 21, EE * 2), dim3(64, 4), 0, stream>>>(inp, emb_w, emb_b, xbuf, stats);
    conv_bnd_kernel<<<dim3(66, EE * 2), dim3(64, 4), 0, stream>>>(inp, emb_w, emb_b, xbuf, stats);
    ln_stats_kernel<<<1, 64, 0, stream>>>(stats);
    scores_fused_kernel<<<1024, 256, 0, stream>>>(xbuf, ln_w, ln_b, wk, wq, stats, sacc);
    softmax_kernel<<<1, 192, 0, stream>>>(sacc, Amat);
    final_kernel<<<NBATCH, 256, 0, stream>>>(xbuf, ln_w, ln_b, wv, wo, bo,
                                             w_out, b_out, stats, Amat, y);
}

// Round 20
// 1247.906 us; speedup vs baseline: 1.0148x; 1.0148x over previous
//
#include <hip/hip_runtime.h>
#include <hip/hip_bf16.h>

#define HH 361
#define WW 720
#define HWP (HH*WW)          // 259920
#define CIN 11
#define CC 32
#define HD 16
#define EE 10
#define NBATCH ((HWP + 63) / 64)   // 4062
#define LN_EPS 1e-5f
#define SELU_ALPHA 1.6732632423543772f
#define SELU_SCALE 1.0507009873554805f
#define SELU_SA (SELU_SCALE * SELU_ALPHA)

typedef float f32x2 __attribute__((ext_vector_type(2)));

// bf16 helpers (round-to-nearest-even pack; cheap unpacks from packed dwords)
static __device__ __forceinline__ unsigned int f2bf(float f) {
    unsigned int u = __float_as_uint(f);
    return (u + 0x7FFFu + ((u >> 16) & 1u)) >> 16;
}
static __device__ __forceinline__ float bflo(unsigned int u) {
    return __uint_as_float(u << 16);
}
static __device__ __forceinline__ float bfhi(unsigned int u) {
    return __uint_as_float(u & 0xffff0000u);
}
static __device__ __forceinline__ float selu_f(float v) {
    // fast SELU via v_exp_f32; abs err <= ~2e-6, invisible vs bf16 storage
    return v > 0.f ? SELU_SCALE * v : SELU_SA * (__expf(v) - 1.f);
}

// ---------------- zero accumulators ----------------
__global__ void zero_kernel(float* __restrict__ p) {
    int t = blockIdx.x * 256 + threadIdx.x;
    if (t < 40 + HD * EE * EE) p[t] = 0.f;
}

// ---------------- conv: INTERIOR blocks (x 1..10, y 1..21), guard-free ----------------
// r16-proven shape (4 rows x 16 ch / thread, half-split grid.z, unroll 1, (256,4)).
// THIS ROUND: accumulators as f32x2 + __builtin_elementwise_fma -> v_pk_fma_f32
// (2 fp32 FMA / instruction): halves the MAC issue count. Channel pairs are
// already consecutive VGPRs from the b128 LDS weight loads -> zero extra moves.
// Bit-identical IEEE fp32 fma semantics. If the compiler declines to pack,
// this degenerates to the proven scalar form (neutral).
__global__ __launch_bounds__(256, 4) void conv_int_kernel(
    const float* __restrict__ inp, const float* __restrict__ emb_w,
    const float* __restrict__ emb_b, unsigned short* __restrict__ xout,
    float* __restrict__ stats)
{
    __shared__ float wlds[CIN * 25 * 16];   // 17.6 KB
    __shared__ float bsm[16];
    __shared__ float red[8];
    const int z = blockIdx.z;
    const int e = z >> 1, half = z & 1;
    const int tid = threadIdx.y * 64 + threadIdx.x;
    for (int t = tid; t < CIN * 25 * 16; t += 256) {
        int u = t & 15; int rest = t >> 4; int k25 = rest % 25; int ci = rest / 25;
        wlds[t] = emb_w[((half * 16 + u) * CIN + ci) * 25 + k25];
    }
    if (tid < 16) bsm[tid] = emb_b[half * 16 + tid];
    __syncthreads();

    const int w  = (blockIdx.x + 1) * 64 + threadIdx.x;    // 64..703
    const int h0 = (blockIdx.y + 1) * 16 + threadIdx.y * 4; // 16..348; halo in-range

    f32x2 acc[4][8];
    #pragma unroll
    for (int hs = 0; hs < 4; ++hs)
        #pragma unroll
        for (int p = 0; p < 8; ++p) {
            acc[hs][p][0] = bsm[2 * p];
            acc[hs][p][1] = bsm[2 * p + 1];
        }

    #pragma unroll 1
    for (int ci = 0; ci < CIN; ++ci) {
        const float* rp2 = inp + ((size_t)(e * CIN + ci)) * HWP + (size_t)(h0 - 2) * WW + (w - 2);
        float in[8][5];
        #pragma unroll
        for (int r = 0; r < 8; ++r) {
            float4 q = *(const float4*)rp2;
            in[r][0] = q.x; in[r][1] = q.y; in[r][2] = q.z; in[r][3] = q.w;
            in[r][4] = rp2[4];
            rp2 += WW;
        }
        #pragma unroll
        for (int kh = 0; kh < 5; ++kh) {
            #pragma unroll
            for (int kw = 0; kw < 5; ++kw) {
                const float* wp = &wlds[(ci * 25 + kh * 5 + kw) * 16];
                const float4 w0 = *(const float4*)(wp);
                const float4 w1 = *(const float4*)(wp + 4);
                const float4 w2 = *(const float4*)(wp + 8);
                const float4 w3 = *(const float4*)(wp + 12);
                const f32x2 wp0 = {w0.x, w0.y}, wp1 = {w0.z, w0.w};
                const f32x2 wp2v = {w1.x, w1.y}, wp3 = {w1.z, w1.w};
                const f32x2 wp4 = {w2.x, w2.y}, wp5 = {w2.z, w2.w};
                const f32x2 wp6 = {w3.x, w3.y}, wp7 = {w3.z, w3.w};
                #pragma unroll
                for (int hs = 0; hs < 4; ++hs) {
                    const float iv = in[hs + kh][kw];
                    const f32x2 ivv = {iv, iv};
                    acc[hs][0] = __builtin_elementwise_fma(ivv, wp0,  acc[hs][0]);
                    acc[hs][1] = __builtin_elementwise_fma(ivv, wp1,  acc[hs][1]);
                    acc[hs][2] = __builtin_elementwise_fma(ivv, wp2v, acc[hs][2]);
                    acc[hs][3] = __builtin_elementwise_fma(ivv, wp3,  acc[hs][3]);
                    acc[hs][4] = __builtin_elementwise_fma(ivv, wp4,  acc[hs][4]);
                    acc[hs][5] = __builtin_elementwise_fma(ivv, wp5,  acc[hs][5]);
                    acc[hs][6] = __builtin_elementwise_fma(ivv, wp6,  acc[hs][6]);
                    acc[hs][7] = __builtin_elementwise_fma(ivv, wp7,  acc[hs][7]);
                }
            }
        }
    }

    float s = 0.f, s2 = 0.f;
    #pragma unroll
    for (int hs = 0; hs < 4; ++hs) {
        const int h = h0 + hs;   // always < HH
        unsigned int pk[8];
        #pragma unroll
        for (int p = 0; p < 8; ++p) {
            float v0 = selu_f(acc[hs][p][0]);
            float v1 = selu_f(acc[hs][p][1]);
            s += v0 + v1; s2 = fmaf(v0, v0, s2); s2 = fmaf(v1, v1, s2);
            pk[p] = f2bf(v0) | (f2bf(v1) << 16);
        }
        uint4* dst = (uint4*)(xout + ((size_t)e * HWP + (size_t)h * WW + w) * CC + half * 16);
        dst[0] = make_uint4(pk[0], pk[1], pk[2], pk[3]);
        dst[1] = make_uint4(pk[4], pk[5], pk[6], pk[7]);
    }
    #pragma unroll
    for (int off = 32; off; off >>= 1) { s += __shfl_down(s, off); s2 += __shfl_down(s2, off); }
    if ((tid & 63) == 0) { red[tid >> 6] = s; red[4 + (tid >> 6)] = s2; }
    __syncthreads();
    if (tid == 0) {
        atomicAdd(&stats[e], red[0] + red[1] + red[2] + red[3]);
        atomicAdd(&stats[EE + e], red[4] + red[5] + red[6] + red[7]);
    }
}

// ---------------- conv: BOUNDARY blocks (frame), guarded path ----------------
__global__ __launch_bounds__(256) void conv_bnd_kernel(
    const float* __restrict__ inp, const float* __restrict__ emb_w,
    const float* __restrict__ emb_b, unsigned short* __restrict__ xout,
    float* __restrict__ stats)
{
    __shared__ float wlds[CIN * 25 * 16];
    __shared__ float bsm[16];
    __shared__ float red[8];
    const int z = blockIdx.y;
    const int e = z >> 1, half = z & 1;
    const int tid = threadIdx.y * 64 + threadIdx.x;
    for (int t = tid; t < CIN * 25 * 16; t += 256) {
        int u = t & 15; int rest = t >> 4; int k25 = rest % 25; int ci = rest / 25;
        wlds[t] = emb_w[((half * 16 + u) * CIN + ci) * 25 + k25];
    }
    if (tid < 16) bsm[tid] = emb_b[half * 16 + tid];
    __syncthreads();

    const int b = blockIdx.x;
    int bx, by;
    if (b < 23)      { bx = 0;      by = b; }
    else if (b < 46) { bx = 11;     by = b - 23; }
    else if (b < 56) { bx = b - 45; by = 0; }
    else             { bx = b - 55; by = 22; }

    const int w  = bx * 64 + threadIdx.x;
    const int h0 = by * 16 + threadIdx.y * 4;
    const bool active = (w < WW);

    int wl[5];
    if (active) {
        #pragma unroll
        for (int d = 0; d < 5; ++d) {
            int ww = w + d - 2; if (ww < 0) ww += WW; if (ww >= WW) ww -= WW; wl[d] = ww;
        }
    }

    float acc[4][16];
    #pragma unroll
    for (int hs = 0; hs < 4; ++hs)
        #pragma unroll
        for (int c = 0; c < 16; ++c) acc[hs][c] = bsm[c];

    if (active) {
        #pragma unroll 1
        for (int ci = 0; ci < CIN; ++ci) {
            const float* ip = inp + ((size_t)(e * CIN + ci)) * HWP;
            float in[8][5];
            #pragma unroll
            for (int r = 0; r < 8; ++r) {
                int hh = h0 + r - 2;
                bool v = (hh >= 0 && hh < HH);
                const float* rp = ip + (size_t)hh * WW;
                #pragma unroll
                for (int d = 0; d < 5; ++d) in[r][d] = v ? rp[wl[d]] : 0.f;
            }
            #pragma unroll
            for (int kh = 0; kh < 5; ++kh) {
                #pragma unroll
                for (int kw = 0; kw < 5; ++kw) {
                    const float* wp = &wlds[(ci * 25 + kh * 5 + kw) * 16];
                    const float4 w0 = *(const float4*)(wp);
                    const float4 w1 = *(const float4*)(wp + 4);
                    const float4 w2 = *(const float4*)(wp + 8);
                    const float4 w3 = *(const float4*)(wp + 12);
                    #pragma unroll
                    for (int hs = 0; hs < 4; ++hs) {
                        const float iv = in[hs + kh][kw];
                        acc[hs][0]  = fmaf(iv, w0.x, acc[hs][0]);
                        acc[hs][1]  = fmaf(iv, w0.y, acc[hs][1]);
                        acc[hs][2]  = fmaf(iv, w0.z, acc[hs][2]);
                        acc[hs][3]  = fmaf(iv, w0.w, acc[hs][3]);
                        acc[hs][4]  = fmaf(iv, w1.x, acc[hs][4]);
                        acc[hs][5]  = fmaf(iv, w1.y, acc[hs][5]);
                        acc[hs][6]  = fmaf(iv, w1.z, acc[hs][6]);
                        acc[hs][7]  = fmaf(iv, w1.w, acc[hs][7]);
                        acc[hs][8]  = fmaf(iv, w2.x, acc[hs][8]);
                        acc[hs][9]  = fmaf(iv, w2.y, acc[hs][9]);
                        acc[hs][10] = fmaf(iv, w2.z, acc[hs][10]);
                        acc[hs][11] = fmaf(iv, w2.w, acc[hs][11]);
                        acc[hs][12] = fmaf(iv, w3.x, acc[hs][12]);
                        acc[hs][13] = fmaf(iv, w3.y, acc[hs][13]);
                        acc[hs][14] = fmaf(iv, w3.z, acc[hs][14]);
                        acc[hs][15] = fmaf(iv, w3.w, acc[hs][15]);
                    }
                }
            }
        }
    }

    float s = 0.f, s2 = 0.f;
    #pragma unroll
    for (int hs = 0; hs < 4; ++hs) {
        const int h = h0 + hs;
        if (active && h < HH) {
            unsigned int pk[8];
            #pragma unroll
            for (int c = 0; c < 16; c += 2) {
                float v0 = selu_f(acc[hs][c]);
                float v1 = selu_f(acc[hs][c + 1]);
                s += v0 + v1; s2 = fmaf(v0, v0, s2); s2 = fmaf(v1, v1, s2);
                pk[c >> 1] = f2bf(v0) | (f2bf(v1) << 16);
            }
            uint4* dst = (uint4*)(xout + ((size_t)e * HWP + (size_t)h * WW + w) * CC + half * 16);
            dst[0] = make_uint4(pk[0], pk[1], pk[2], pk[3]);
            dst[1] = make_uint4(pk[4], pk[5], pk[6], pk[7]);
        }
    }
    #pragma unroll
    for (int off = 32; off; off >>= 1) { s += __shfl_down(s, off); s2 += __shfl_down(s2, off); }
    if ((tid & 63) == 0) { red[tid >> 6] = s; red[4 + (tid >> 6)] = s2; }
    __syncthreads();
    if (tid == 0) {
        atomicAdd(&stats[e], red[0] + red[1] + red[2] + red[3]);
        atomicAdd(&stats[EE + e], red[4] + red[5] + red[6] + red[7]);
    }
}

// ---------------- finalize LN stats ----------------
__global__ void ln_stats_kernel(float* __restrict__ stats) {
    int e = threadIdx.x;
    if (e < EE) {
        const float N = (float)CC * (float)HWP;
        float mu = stats[e] / N;
        float var = stats[EE + e] / N - mu * mu;
        stats[2 * EE + e] = mu;
        stats[3 * EE + e] = rsqrtf(var + LN_EPS);
    }
}

// ---------------- fused k,q + scores ----------------
__global__ __launch_bounds__(256) void scores_fused_kernel(
    const unsigned short* __restrict__ x, const float* __restrict__ ln_w,
    const float* __restrict__ ln_b, const float* __restrict__ wk,
    const float* __restrict__ wq, const float* __restrict__ stats,
    float* __restrict__ sacc)
{
    __shared__ float wksT[CC * HD], wqsT[CC * HD];   // [ch][c]
    __shared__ unsigned int stage[64][164];          // k at [e*8+d], q at [80+e*8+d]
    for (int t = threadIdx.x; t < CC * HD; t += 256) {
        int ch = t >> 4, c = t & 15;
        wksT[t] = wk[c * CC + ch];
        wqsT[t] = wq[c * CC + ch];
    }
    float mu[EE], rs[EE];
    #pragma unroll
    for (int e2 = 0; e2 < EE; ++e2) { mu[e2] = stats[2 * EE + e2]; rs[e2] = stats[3 * EE + e2]; }

    const int wv = threadIdx.x >> 6;
    const int lane = threadIdx.x & 63;
    const int pr = threadIdx.x >> 1;
    const int hf = threadIdx.x & 1;
    const int pi = pr / EE, pj = pr % EE;
    float acc[8] = {0.f,0.f,0.f,0.f,0.f,0.f,0.f,0.f};
    __syncthreads();

    #pragma unroll 1
    for (int b = blockIdx.x; b < NBATCH; b += gridDim.x) {
        const int pix = b * 64 + lane;
        const bool valid = pix < HWP;
        float lw[CC], lb[CC];
        #pragma unroll
        for (int ch = 0; ch < CC; ++ch) {
            lw[ch] = valid ? ln_w[(size_t)ch * HWP + pix] : 0.f;
            lb[ch] = valid ? ln_b[(size_t)ch * HWP + pix] : 0.f;
        }
        #pragma unroll 1
        for (int g = 0; g < 5; ++g) {
            unsigned int xr[2][16];
            #pragma unroll
            for (int eg = 0; eg < 2; ++eg) {
                const int e2 = g * 2 + eg;
                if (valid) {
                    const uint4* xp = (const uint4*)(x + ((size_t)e2 * HWP + pix) * CC);
                    uint4 a0 = xp[0], a1 = xp[1], a2 = xp[2], a3 = xp[3];
                    xr[eg][0]=a0.x; xr[eg][1]=a0.y; xr[eg][2]=a0.z; xr[eg][3]=a0.w;
                    xr[eg][4]=a1.x; xr[eg][5]=a1.y; xr[eg][6]=a1.z; xr[eg][7]=a1.w;
                    xr[eg][8]=a2.x; xr[eg][9]=a2.y; xr[eg][10]=a2.z; xr[eg][11]=a2.w;
                    xr[eg][12]=a3.x; xr[eg][13]=a3.y; xr[eg][14]=a3.z; xr[eg][15]=a3.w;
                } else {
                    #pragma unroll
                    for (int k2 = 0; k2 < 16; ++k2) xr[eg][k2] = 0u;
                }
            }
            float ka[2][4], qa[2][4];
            #pragma unroll
            for (int eg = 0; eg < 2; ++eg)
                #pragma unroll
                for (int u = 0; u < 4; ++u) { ka[eg][u] = 0.f; qa[eg][u] = 0.f; }
            #pragma unroll
            for (int ch = 0; ch < CC; ++ch) {
                const float4 wk4 = *(const float4*)&wksT[ch * HD + wv * 4];
                const float4 wq4 = *(const float4*)&wqsT[ch * HD + wv * 4];
                #pragma unroll
                for (int eg = 0; eg < 2; ++eg) {
                    const int e2 = g * 2 + eg;
                    unsigned int u = xr[eg][ch >> 1];
                    float xv = (ch & 1) ? bfhi(u) : bflo(u);
                    float lnv = fmaf((xv - mu[e2]) * rs[e2], lw[ch], lb[ch]);
                    ka[eg][0] = fmaf(wk4.x, lnv, ka[eg][0]);
                    ka[eg][1] = fmaf(wk4.y, lnv, ka[eg][1]);
                    ka[eg][2] = fmaf(wk4.z, lnv, ka[eg][2]);
                    ka[eg][3] = fmaf(wk4.w, lnv, ka[eg][3]);
                    qa[eg][0] = fmaf(wq4.x, lnv, qa[eg][0]);
                    qa[eg][1] = fmaf(wq4.y, lnv, qa[eg][1]);
                    qa[eg][2] = fmaf(wq4.z, lnv, qa[eg][2]);
                    qa[eg][3] = fmaf(wq4.w, lnv, qa[eg][3]);
                }
            }
            #pragma unroll
            for (int eg = 0; eg < 2; ++eg) {
                const int e2 = g * 2 + eg;
                uint2 kp, qp;
                kp.x = f2bf(fmaxf(ka[eg][0], 0.f)) | (f2bf(fmaxf(ka[eg][1], 0.f)) << 16);
                kp.y = f2bf(fmaxf(ka[eg][2], 0.f)) | (f2bf(fmaxf(ka[eg][3], 0.f)) << 16);
                qp.x = f2bf(fmaxf(qa[eg][0], 0.f)) | (f2bf(fmaxf(qa[eg][1], 0.f)) << 16);
                qp.y = f2bf(fmaxf(qa[eg][2], 0.f)) | (f2bf(fmaxf(qa[eg][3], 0.f)) << 16);
                *(uint2*)&stage[lane][e2 * 8 + wv * 2] = kp;
                *(uint2*)&stage[lane][80 + e2 * 8 + wv * 2] = qp;
            }
        }
        __syncthreads();
        if (pr < 100) {
            #pragma unroll 8
            for (int p = 0; p < 64; ++p) {
                uint4 kk = *(const uint4*)&stage[p][pi * 8 + hf * 4];
                uint4 qq = *(const uint4*)&stage[p][80 + pj * 8 + hf * 4];
                acc[0] = fmaf(bflo(kk.x), bflo(qq.x), acc[0]);
                acc[1] = fmaf(bfhi(kk.x), bfhi(qq.x), acc[1]);
                acc[2] = fmaf(bflo(kk.y), bflo(qq.y), acc[2]);
                acc[3] = fmaf(bfhi(kk.y), bfhi(qq.y), acc[3]);
                acc[4] = fmaf(bflo(kk.z), bflo(qq.z), acc[4]);
                acc[5] = fmaf(bfhi(kk.z), bfhi(qq.z), acc[5]);
                acc[6] = fmaf(bflo(kk.w), bflo(qq.w), acc[6]);
                acc[7] = fmaf(bfhi(kk.w), bfhi(qq.w), acc[7]);
            }
        }
        __syncthreads();
    }
    if (pr < 100) {
        #pragma unroll
        for (int c2 = 0; c2 < 8; ++c2)
            atomicAdd(&sacc[((hf * 8 + c2) * EE + pi) * EE + pj], acc[c2]);
    }
}

// ---------------- softmax over i + fold A = delta + w - 1/E ----------------
__global__ void softmax_kernel(const float* __restrict__ sacc, float* __restrict__ A)
{
    int t = threadIdx.x;
    if (t >= HD * EE) return;
    int c = t / EE, j = t - c * EE;
    const float norm = (float)(1.0 / 509.8234988357398);  // 1/sqrt(361*720)
    float sv[EE];
    float mx = -1e30f;
    #pragma unroll
    for (int i = 0; i < EE; ++i) { sv[i] = sacc[(c * EE + i) * EE + j] * norm; mx = fmaxf(mx, sv[i]); }
    float sum = 0.f;
    #pragma unroll
    for (int i = 0; i < EE; ++i) { sv[i] = expf(sv[i] - mx); sum += sv[i]; }
    float inv = 1.f / sum;
    #pragma unroll
    for (int i = 0; i < EE; ++i) {
        float wgt = sv[i] * inv;
        A[(c * EE + i) * EE + j] = wgt - (1.f / (float)EE) + (i == j ? 1.f : 0.f);
    }
}

// ---------------- fused final v3: 4-way head split, tv-accumulate, tiny state ----------------
__global__ __launch_bounds__(256) void final_kernel(
    const unsigned short* __restrict__ x, const float* __restrict__ ln_w,
    const float* __restrict__ ln_b, const float* __restrict__ wvw,
    const float* __restrict__ wo, const float* __restrict__ bo,
    const float* __restrict__ w_out, const float* __restrict__ b_out,
    const float* __restrict__ stats, const float* __restrict__ A,
    float* __restrict__ y)
{
    __shared__ float As_l[HD * 120];        // [c][e][j pad 12]  7.5 KB
    __shared__ float wvsT[CC * HD];         // [ch][c]           2 KB
    __shared__ float wos[HD * CC];          // [c][ch]           2 KB
    __shared__ float lwlds[64 * 36];        // [px][ch pad 36]   9 KB
    __shared__ float bos[CC];
    __shared__ float wouts[CC];
    const int tid = threadIdx.x;
    const int pixbase = blockIdx.x * 64;
    for (int t = tid; t < CC * HD; t += 256) {
        int ch = t >> 4, c = t & 15;
        wvsT[t] = wvw[c * CC + ch];
        wos[c * CC + ch] = wo[ch * HD + c];
    }
    for (int t = tid; t < HD * EE * EE; t += 256) {
        int c = t / 100, rest = t % 100;
        As_l[c * 120 + (rest / 10) * 12 + (rest % 10)] = A[t];
    }
    for (int t = tid; t < 64 * CC; t += 256) {
        int px = t & 63, ch = t >> 6;
        int pp = pixbase + px;
        lwlds[px * 36 + ch] = (pp < HWP) ? ln_w[(size_t)ch * HWP + pp] : 0.f;
    }
    if (tid < CC) { bos[tid] = bo[tid]; wouts[tid] = w_out[tid]; }
    __syncthreads();

    const int wvi = tid >> 6, lane = tid & 63;
    const int px = lane & 15;          // pixel slot within wave
    const int qg = lane >> 4;          // head/channel quarter 0..3
    const int pxl = wvi * 16 + px;     // local pixel 0..63
    const int pix = pixbase + pxl;
    const bool valid = pix < HWP;

    // ---- cb0/cb1 for this lane's 4 heads
    float cb0[4] = {0.f, 0.f, 0.f, 0.f}, cb1[4] = {0.f, 0.f, 0.f, 0.f};
    #pragma unroll
    for (int ch = 0; ch < CC; ++ch) {
        float lwv = lwlds[pxl * 36 + ch];
        float lbv = valid ? ln_b[(size_t)ch * HWP + pix] : 0.f;
        const float4 w4 = *(const float4*)&wvsT[ch * HD + qg * 4];
        cb1[0] = fmaf(w4.x, lwv, cb1[0]); cb1[1] = fmaf(w4.y, lwv, cb1[1]);
        cb1[2] = fmaf(w4.z, lwv, cb1[2]); cb1[3] = fmaf(w4.w, lwv, cb1[3]);
        cb0[0] = fmaf(w4.x, lbv, cb0[0]); cb0[1] = fmaf(w4.y, lbv, cb0[1]);
        cb0[2] = fmaf(w4.z, lbv, cb0[2]); cb0[3] = fmaf(w4.w, lbv, cb0[3]);
    }

    float tvacc[EE][4];
    #pragma unroll
    for (int j = 0; j < EE; ++j)
        #pragma unroll
        for (int r = 0; r < 4; ++r) tvacc[j][r] = 0.f;

    // ---- Phase A: members in pairs; v transient, folded into tvacc immediately
    #pragma unroll 1
    for (int ep = 0; ep < 5; ++ep) {
        const int e0 = 2 * ep, e1 = 2 * ep + 1;
        const float mu0 = stats[2 * EE + e0], rs0 = stats[3 * EE + e0];
        const float mu1 = stats[2 * EE + e1], rs1 = stats[3 * EE + e1];
        const uint4* xp0 = (const uint4*)(x + ((size_t)e0 * HWP + pix) * CC);
        const uint4* xp1 = (const uint4*)(x + ((size_t)e1 * HWP + pix) * CC);
        float a0[4] = {0.f, 0.f, 0.f, 0.f}, a1[4] = {0.f, 0.f, 0.f, 0.f};
        #pragma unroll
        for (int hx = 0; hx < 2; ++hx) {
            unsigned int xr0[8], xr1[8];
            if (valid) {
                uint4 b0 = xp0[2 * hx], b1 = xp0[2 * hx + 1];
                xr0[0]=b0.x; xr0[1]=b0.y; xr0[2]=b0.z; xr0[3]=b0.w;
                xr0[4]=b1.x; xr0[5]=b1.y; xr0[6]=b1.z; xr0[7]=b1.w;
                uint4 c0 = xp1[2 * hx], c1 = xp1[2 * hx + 1];
                xr1[0]=c0.x; xr1[1]=c0.y; xr1[2]=c0.z; xr1[3]=c0.w;
                xr1[4]=c1.x; xr1[5]=c1.y; xr1[6]=c1.z; xr1[7]=c1.w;
            } else {
                #pragma unroll
                for (int k2 = 0; k2 < 8; ++k2) { xr0[k2] = 0u; xr1[k2] = 0u; }
            }
            #pragma unroll
            for (int c2 = 0; c2 < 16; ++c2) {
                const int ch = hx * 16 + c2;
                const float lwv = lwlds[pxl * 36 + ch];
                const float4 w4 = *(const float4*)&wvsT[ch * HD + qg * 4];
                unsigned int u0 = xr0[c2 >> 1], u1 = xr1[c2 >> 1];
                float t0 = ((c2 & 1) ? bfhi(u0) : bflo(u0)) * lwv;
                float t1 = ((c2 & 1) ? bfhi(u1) : bflo(u1)) * lwv;
                a0[0] = fmaf(w4.x, t0, a0[0]); a0[1] = fmaf(w4.y, t0, a0[1]);
                a0[2] = fmaf(w4.z, t0, a0[2]); a0[3] = fmaf(w4.w, t0, a0[3]);
                a1[0] = fmaf(w4.x, t1, a1[0]); a1[1] = fmaf(w4.y, t1, a1[1]);
                a1[2] = fmaf(w4.z, t1, a1[2]); a1[3] = fmaf(w4.w, t1, a1[3]);
            }
        }
        const float mrs0 = mu0 * rs0, mrs1 = mu1 * rs1;
        #pragma unroll
        for (int r = 0; r < 4; ++r) {
            const float v0r = rs0 * a0[r] - mrs0 * cb1[r] + cb0[r];
            const float v1r = rs1 * a1[r] - mrs1 * cb1[r] + cb0[r];
            const float* p0 = &As_l[(qg * 4 + r) * 120 + e0 * 12];
            const float* p1 = &As_l[(qg * 4 + r) * 120 + e1 * 12];
            float4 A0a = *(const float4*)p0; float4 A0b = *(const float4*)(p0 + 4);
            float2 A0c = *(const float2*)(p0 + 8);
            float4 A1a = *(const float4*)p1; float4 A1b = *(const float4*)(p1 + 4);
            float2 A1c = *(const float2*)(p1 + 8);
            tvacc[0][r] = fmaf(A0a.x, v0r, fmaf(A1a.x, v1r, tvacc[0][r]));
            tvacc[1][r] = fmaf(A0a.y, v0r, fmaf(A1a.y, v1r, tvacc[1][r]));
            tvacc[2][r] = fmaf(A0a.z, v0r, fmaf(A1a.z, v1r, tvacc[2][r]));
            tvacc[3][r] = fmaf(A0a.w, v0r, fmaf(A1a.w, v1r, tvacc[3][r]));
            tvacc[4][r] = fmaf(A0b.x, v0r, fmaf(A1b.x, v1r, tvacc[4][r]));
            tvacc[5][r] = fmaf(A0b.y, v0r, fmaf(A1b.y, v1r, tvacc[5][r]));
            tvacc[6][r] = fmaf(A0b.z, v0r, fmaf(A1b.z, v1r, tvacc[6][r]));
            tvacc[7][r] = fmaf(A0b.w, v0r, fmaf(A1b.w, v1r, tvacc[7][r]));
            tvacc[8][r] = fmaf(A0c.x, v0r, fmaf(A1c.x, v1r, tvacc[8][r]));
            tvacc[9][r] = fmaf(A0c.y, v0r, fmaf(A1c.y, v1r, tvacc[9][r]));
        }
    }

    // ---- Phase B: per output member j (fully unrolled; tvacc static indices)
    const float boutv = b_out[0];
    #pragma unroll
    for (int j = 0; j < EE; ++j) {
        float tvj[16];
        #pragma unroll
        for (int c = 0; c < 16; ++c)
            tvj[c] = __shfl(tvacc[j][c & 3], (c >> 2) * 16 + px, 64);
        unsigned int xj[4];
        if (valid) {
            uint4 b = *(const uint4*)(x + ((size_t)j * HWP + pix) * CC + qg * 8);
            xj[0] = b.x; xj[1] = b.y; xj[2] = b.z; xj[3] = b.w;
        } else {
            #pragma unroll
            for (int k2 = 0; k2 < 4; ++k2) xj[k2] = 0u;
        }
        float o[8];
        #pragma unroll
        for (int k = 0; k < 8; ++k) {
            unsigned int u = xj[k >> 1];
            float xv = (k & 1) ? bfhi(u) : bflo(u);
            o[k] = bos[qg * 8 + k] + xv;
        }
        #pragma unroll
        for (int c = 0; c < 16; ++c) {
            const float tvc = tvj[c];
            const float4 wv0 = *(const float4*)&wos[c * CC + qg * 8];
            const float4 wv1 = *(const float4*)&wos[c * CC + qg * 8 + 4];
            o[0] = fmaf(wv0.x, tvc, o[0]); o[1] = fmaf(wv0.y, tvc, o[1]);
            o[2] = fmaf(wv0.z, tvc, o[2]); o[3] = fmaf(wv0.w, tvc, o[3]);
            o[4] = fmaf(wv1.x, tvc, o[4]); o[5] = fmaf(wv1.y, tvc, o[5]);
            o[6] = fmaf(wv1.z, tvc, o[6]); o[7] = fmaf(wv1.w, tvc, o[7]);
        }
        float yp = 0.f;
        #pragma unroll
        for (int k = 0; k < 8; ++k) yp = fmaf(wouts[qg * 8 + k], fmaxf(o[k], 0.f), yp);
        yp += __shfl_xor(yp, 16);
        yp += __shfl_xor(yp, 32);
        if (qg == 0 && valid) y[(size_t)j * HWP + pix] = yp + boutv;
    }
}

extern "C" void kernel_launch(void* const* d_in, const int* in_sizes, int n_in,
                              void* d_out, int out_size, void* d_ws, size_t ws_size,
                              hipStream_t stream)
{
    const float* inp   = (const float*)d_in[0];
    const float* emb_w = (const float*)d_in[1];
    const float* emb_b = (const float*)d_in[2];
    const float* ln_w  = (const float*)d_in[3];
    const float* ln_b  = (const float*)d_in[4];
    const float* wv    = (const float*)d_in[5];
    const float* wk    = (const float*)d_in[6];
    const float* wq    = (const float*)d_in[7];
    const float* wo    = (const float*)d_in[8];
    const float* bo    = (const float*)d_in[9];
    const float* w_out = (const float*)d_in[10];
    const float* b_out = (const float*)d_in[11];
    float* y = (float*)d_out;

    // ws: x bf16 channel-last [E][HW][32] = 166,348,800 B; then stats(40)+sacc(1600)+A(1600)
    unsigned short* xbuf = (unsigned short*)d_ws;
    float* stats = (float*)((char*)d_ws + (size_t)EE * HWP * CC * 2);
    float* sacc  = stats + 40;
    float* Amat  = sacc + HD * EE * EE;

    zero_kernel<<<7, 256, 0, stream>>>(stats);
    conv_int_kernel<<<dim3(10, 21, EE * 2), dim3(64, 4), 0, stream>>>(inp, emb_w, emb_b, xbuf, stats);
    conv_bnd_kernel<<<dim3(66, EE * 2), dim3(64, 4), 0, stream>>>(inp, emb_w, emb_b, xbuf, stats);
    ln_stats_kernel<<<1, 64, 0, stream>>>(stats);
    scores_fused_kernel<<<1024, 256, 0, stream>>>(xbuf, ln_w, ln_b, wk, wq, stats, sacc);
    softmax_kernel<<<1, 192, 0, stream>>>(sacc, Amat);
    final_kernel<<<NBATCH, 256, 0, stream>>>(xbuf, ln_w, ln_b, wv, wo, bo,
                                             w_out, b_out, stats, Amat, y);
}